// Round 3
// baseline (351.712 us; speedup 1.0000x reference)
//
#include <hip/hip_runtime.h>
#include <stdint.h>

// B=4, n=8192, d=512.  Algebraic form:
//   G_b = X_b^T X_b                       [512,512] sym, K=8192
//   kvt_b = Wv * (G_b*scale) * Wth^T      [e][d], scale = 1/(n*sqrt(d))
//   meanV_b[e] = colmean(X_b) . Wv[e][:]
//   out = X_b @ kvt_b(B-layout) + meanV
// Layouts (all K-inner for global_load_lds staging):
//   Xb  [32768][512] bf16        A for final GEMM
//   Xt  [4][512][8192] bf16      A=B for G GEMM (n-inner)
//   Gb  [4][512][512] bf16       scaled, full (mirrored from upper tiles)
//   Ht  [4][512][512] bf16       Wv*Gs
//   kvt [4][512][512] bf16       (e-major, d-inner) B for final GEMM

typedef __bf16 bf16x8 __attribute__((ext_vector_type(8)));
typedef float f32x4 __attribute__((ext_vector_type(4)));
typedef unsigned short u16x4 __attribute__((ext_vector_type(4)));
typedef unsigned short u16x8 __attribute__((ext_vector_type(8)));

#define BM 128
#define BN 128
#define BK 32

__device__ __forceinline__ unsigned short f2bf(float f) {
  union { float f; unsigned int u; } c; c.f = f;
  unsigned int u = c.u;
  return (unsigned short)((u + 0x7FFFu + ((u >> 16) & 1u)) >> 16);  // RNE
}

__device__ __forceinline__ void gld16(const void* g, void* l) {
  using gptr_t = const __attribute__((address_space(1))) void*;
  using lptr_t = __attribute__((address_space(3))) void*;
  __builtin_amdgcn_global_load_lds((gptr_t)(uintptr_t)g,
                                   (lptr_t)(uint32_t)(uintptr_t)l, 16, 0, 0);
}

// 128x128 tile GEMM core: C[m][n] = sum_k A[m0+m][k] * B[n0+n][k]
// Two BK=32 tiles staged per barrier pair (halves barrier drains).
// K must be a multiple of 64. If sameAB, B staging is skipped (B==A tile).
__device__ __forceinline__ void gemm_tile(const unsigned short* __restrict__ A, int lda,
                                          const unsigned short* __restrict__ B, int ldb,
                                          int K, int m0, int n0, f32x4 (&acc)[4][4],
                                          bool sameAB) {
  __shared__ unsigned short sA[2][BM * BK];
  __shared__ unsigned short sB[2][BN * BK];
  const int tid = threadIdx.x;
  const int lane = tid & 63;
  const int w = tid >> 6;
  const int wm = w >> 1, wn = w & 1;
  const int quad = lane >> 4, l16 = lane & 15;

#pragma unroll
  for (int mi = 0; mi < 4; mi++)
#pragma unroll
    for (int ni = 0; ni < 4; ni++) acc[mi][ni] = f32x4{0.f, 0.f, 0.f, 0.f};

  for (int kt = 0; kt < K; kt += 2 * BK) {
#pragma unroll
    for (int h = 0; h < 2; h++) {
#pragma unroll
      for (int j = 0; j < 2; j++) {
        const int slot = w * 128 + j * 64 + lane;
        const int row = slot >> 2;
        const int col = (slot & 3) * 8;
        const int kc = kt + h * BK + col;
        gld16(A + (size_t)(m0 + row) * lda + kc,
              (char*)sA[h] + (size_t)(w * 128 + j * 64) * 16);
        if (!sameAB)
          gld16(B + (size_t)(n0 + row) * ldb + kc,
                (char*)sB[h] + (size_t)(w * 128 + j * 64) * 16);
      }
    }
    __syncthreads();

#pragma unroll
    for (int h = 0; h < 2; h++) {
      const unsigned short* bs = sameAB ? sA[h] : sB[h];
      bf16x8 af[4], bfr[4];
#pragma unroll
      for (int mi = 0; mi < 4; mi++)
        af[mi] = *(const bf16x8*)&sA[h][(wm * 64 + mi * 16 + l16) * BK + quad * 8];
#pragma unroll
      for (int ni = 0; ni < 4; ni++)
        bfr[ni] = *(const bf16x8*)&bs[(wn * 64 + ni * 16 + l16) * BK + quad * 8];
#pragma unroll
      for (int mi = 0; mi < 4; mi++)
#pragma unroll
        for (int ni = 0; ni < 4; ni++)
          acc[mi][ni] = __builtin_amdgcn_mfma_f32_16x16x32_bf16(af[mi], bfr[ni],
                                                                acc[mi][ni], 0, 0, 0);
    }
    __syncthreads();
  }
}

// ---- prep: X fp32 -> Xb bf16 + Xt bf16 (per-batch transpose) + col-sum atomics ----
__global__ __launch_bounds__(256) void prep_kernel(const float* __restrict__ X,
                                                   unsigned short* __restrict__ Xb,
                                                   unsigned short* __restrict__ Xt,
                                                   float* __restrict__ mean_acc) {
  __shared__ unsigned short sT[64 * 64];
  const int t = threadIdx.x;
  const int n0 = blockIdx.x * 64, d0 = blockIdx.y * 64;
  const int b = n0 >> 13, nb = n0 & 8191;
  const int r0 = (t >> 4) * 4, c0 = (t & 15) * 4;
  f32x4 v[4];
#pragma unroll
  for (int i = 0; i < 4; i++)
    v[i] = *(const f32x4*)(X + (size_t)(n0 + r0 + i) * 512 + d0 + c0);
  // Xb (row-major cast), coalesced 8B stores
#pragma unroll
  for (int i = 0; i < 4; i++) {
    u16x4 o;
#pragma unroll
    for (int j = 0; j < 4; j++) o[j] = f2bf(v[i][j]);
    *(u16x4*)(Xb + (size_t)(n0 + r0 + i) * 512 + d0 + c0) = o;
  }
  // column partial sums (over this thread's 4 rows), reduce across wave rows
  float cs[4];
#pragma unroll
  for (int j = 0; j < 4; j++) cs[j] = v[0][j] + v[1][j] + v[2][j] + v[3][j];
#pragma unroll
  for (int j = 0; j < 4; j++) {
    cs[j] += __shfl_xor(cs[j], 16);
    cs[j] += __shfl_xor(cs[j], 32);
  }
  if ((t & 63) < 16) {
#pragma unroll
    for (int j = 0; j < 4; j++)
      atomicAdd(mean_acc + b * 512 + d0 + c0 + j, cs[j]);
  }
  // transposed into LDS, XOR swizzle in 8-elem blocks (keeps u16x8 reads aligned)
#pragma unroll
  for (int j = 0; j < 4; j++) {
    u16x4 wv;
#pragma unroll
    for (int i = 0; i < 4; i++) wv[i] = f2bf(v[i][j]);
    const int c = c0 + j;
    const int rsw = r0 ^ (c & 0x38);
    *(u16x4*)&sT[c * 64 + rsw] = wv;
  }
  __syncthreads();
  // Xt stores: thread t -> rows c, c+32 (d-index), 8 n-elems each, 16B stores
  const int cr = t >> 3, p = t & 7;
#pragma unroll
  for (int h = 0; h < 2; h++) {
    const int c = cr + h * 32;
    const int phys = (p * 8) ^ (c & 0x38);
    u16x8 val = *(const u16x8*)&sT[c * 64 + phys];
    *(u16x8*)(Xt + (size_t)(b * 512 + d0 + c) * 8192 + nb + p * 8) = val;
  }
}

// ---- W casts + mean accumulator zeroing, one launch ----
__global__ __launch_bounds__(256) void prep_w_kernel(const float* __restrict__ Wv,
                                                     const float* __restrict__ Wth,
                                                     unsigned short* __restrict__ Wvb,
                                                     unsigned short* __restrict__ Wtb,
                                                     float* __restrict__ mean_acc) {
  const int blk = blockIdx.x;
  const int t = threadIdx.x;
  if (blk == 256) {
    f32x4 z = f32x4{0.f, 0.f, 0.f, 0.f};
    *(f32x4*)(mean_acc + t * 8) = z;
    *(f32x4*)(mean_acc + t * 8 + 4) = z;
    return;
  }
  const float* src = (blk < 128) ? Wv : Wth;
  unsigned short* dst = (blk < 128) ? Wvb : Wtb;
  const int i = (blk & 127) * 256 + t;
  const f32x4* pp = (const f32x4*)(src + (size_t)i * 8);
  f32x4 v0 = pp[0], v1 = pp[1];
  u16x8 o;
  o[0] = f2bf(v0[0]); o[1] = f2bf(v0[1]); o[2] = f2bf(v0[2]); o[3] = f2bf(v0[3]);
  o[4] = f2bf(v1[0]); o[5] = f2bf(v1[1]); o[6] = f2bf(v1[2]); o[7] = f2bf(v1[3]);
  *(u16x8*)(dst + (size_t)i * 8) = o;
}

// ---- G = Xt Xt^T (per batch), split-K=16, upper tiles only ----
static __device__ const int TI[10] = {0, 0, 0, 0, 1, 1, 1, 2, 2, 3};
static __device__ const int TJ[10] = {0, 1, 2, 3, 1, 2, 3, 2, 3, 3};

__global__ __launch_bounds__(256) void g_gemm_kernel(const unsigned short* __restrict__ Xt,
                                                     float* __restrict__ G_part) {
  const int t = blockIdx.x;        // 0..9 upper tile
  const int z = blockIdx.y;        // b*16 + s
  const int b = z >> 4, s = z & 15;
  const int m0 = TI[t] * 128, n0 = TJ[t] * 128;
  const unsigned short* A = Xt + (size_t)b * 512 * 8192 + (size_t)s * 512;
  f32x4 acc[4][4];
  gemm_tile(A, 8192, A, 8192, 512, m0, n0, acc, m0 == n0);
  float* Cp = G_part + ((size_t)z * 10 + t) * 16384;  // tile stored [n_local][m_local]
  const int tid = threadIdx.x, lane = tid & 63, w = tid >> 6;
  const int wm = w >> 1, wn = w & 1, quad = lane >> 4, l16 = lane & 15;
#pragma unroll
  for (int mi = 0; mi < 4; mi++)
#pragma unroll
    for (int ni = 0; ni < 4; ni++) {
      const int ml = wm * 64 + mi * 16 + quad * 4;
      const int nl = wn * 64 + ni * 16 + l16;
      *(f32x4*)(Cp + (size_t)nl * 128 + ml) = acc[mi][ni];
    }
}

// sum slices, scale, cast bf16, write G + mirror
__global__ __launch_bounds__(256) void g_fin_kernel(const float* __restrict__ G_part,
                                                    unsigned short* __restrict__ Gb) {
  const int blk = blockIdx.x;  // 4*10*8
  const int b = blk / 80, rem = blk % 80;
  const int t = rem >> 3, cc = rem & 7;
  const int i = TI[t], j = TJ[t];
  const int m0 = i * 128, n0 = j * 128;
  const int tid = threadIdx.x;
  const int np = cc * 16 + (tid >> 4);
  const int mp = (tid & 15) * 8;
  f32x4 s0 = f32x4{0.f, 0.f, 0.f, 0.f}, s1 = f32x4{0.f, 0.f, 0.f, 0.f};
#pragma unroll
  for (int s = 0; s < 16; s++) {
    const float* p = G_part + (((size_t)(b * 16 + s)) * 10 + t) * 16384 + (size_t)np * 128 + mp;
    s0 += *(const f32x4*)p;
    s1 += *(const f32x4*)(p + 4);
  }
  const float scale = (float)(1.0 / (8192.0 * 22.627416997969522));
  unsigned short h[8];
#pragma unroll
  for (int r = 0; r < 4; r++) { h[r] = f2bf(s0[r] * scale); h[r + 4] = f2bf(s1[r] * scale); }
  unsigned short* Gbb = Gb + (size_t)b * 262144;
#pragma unroll
  for (int r = 0; r < 8; r++)
    Gbb[(size_t)(m0 + mp + r) * 512 + (n0 + np)] = h[r];
  if (i != j) {
    u16x8 o;
#pragma unroll
    for (int r = 0; r < 8; r++) o[r] = h[r];
    *(u16x8*)(Gbb + (size_t)(n0 + np) * 512 + (m0 + mp)) = o;
  }
}

// small batched GEMM, row-major bf16 C: C[m][n] = sum_k A[m][k]B[n][k], all 512
__global__ __launch_bounds__(256) void gemm_rm_kernel(const unsigned short* __restrict__ A,
                                                      const unsigned short* __restrict__ B,
                                                      unsigned short* __restrict__ C,
                                                      size_t Abs, size_t Bbs) {
  const int b = blockIdx.z;
  const int m0 = blockIdx.x * BM, n0 = blockIdx.y * BN;
  f32x4 acc[4][4];
  gemm_tile(A + (size_t)b * Abs, 512, B + (size_t)b * Bbs, 512, 512, m0, n0, acc, false);
  unsigned short* Cb = C + (size_t)b * 262144;
  const int tid = threadIdx.x, lane = tid & 63, w = tid >> 6;
  const int wm = w >> 1, wn = w & 1, quad = lane >> 4, l16 = lane & 15;
#pragma unroll
  for (int mi = 0; mi < 4; mi++)
#pragma unroll
    for (int ni = 0; ni < 4; ni++) {
      const int m = m0 + wm * 64 + mi * 16 + quad * 4;
      const int n = n0 + wn * 64 + ni * 16 + l16;
#pragma unroll
      for (int r = 0; r < 4; r++)
        Cb[(size_t)(m + r) * 512 + n] = f2bf(acc[mi][ni][r]);
    }
}

// final: out[m][e] = sum_d Xb[m][d]*kvt_b[e][d] + meanV[b][e]
__global__ __launch_bounds__(256) void gemm_out_kernel(
    const unsigned short* __restrict__ Xb, const unsigned short* __restrict__ kvt,
    const float* __restrict__ meanV, float* __restrict__ out) {
  const int m0 = blockIdx.x * BM, n0 = blockIdx.y * BN;
  const int b = blockIdx.x >> 6;
  const unsigned short* Bm = kvt + (size_t)b * 262144;
  f32x4 acc[4][4];
  gemm_tile(Xb, 512, Bm, 512, 512, m0, n0, acc, false);
  const int tid = threadIdx.x, lane = tid & 63, w = tid >> 6;
  const int wm = w >> 1, wn = w & 1, quad = lane >> 4, l16 = lane & 15;
#pragma unroll
  for (int ni = 0; ni < 4; ni++) {
    const int e = n0 + wn * 64 + ni * 16 + l16;
    const float mu = meanV[b * 512 + e];
#pragma unroll
    for (int mi = 0; mi < 4; mi++) {
      const int m = m0 + wm * 64 + mi * 16 + quad * 4;
#pragma unroll
      for (int r = 0; r < 4; r++)
        out[(size_t)(m + r) * 512 + e] = acc[mi][ni][r] + mu;
    }
  }
}

// meanV[b*512+e] = (1/8192) * sum_d mean_acc[b*512+d] * Wv[e*512+d]  (fp32)
__global__ __launch_bounds__(256) void meanv_kernel(const float* __restrict__ mean_acc,
                                                    const float* __restrict__ Wv,
                                                    float* __restrict__ meanV) {
  const int idx = blockIdx.x * 256 + threadIdx.x;
  const int b = idx >> 9, e = idx & 511;
  const float* mx = mean_acc + b * 512;
  const float* wr = Wv + (size_t)e * 512;
  float s = 0.f;
  for (int d = 0; d < 512; d += 4) {
    f32x4 a = *(const f32x4*)(mx + d);
    f32x4 w = *(const f32x4*)(wr + d);
    s += a[0] * w[0] + a[1] * w[1] + a[2] * w[2] + a[3] * w[3];
  }
  meanV[idx] = s * (1.f / 8192.f);
}

extern "C" void kernel_launch(void* const* d_in, const int* in_sizes, int n_in,
                              void* d_out, int out_size, void* d_ws, size_t ws_size,
                              hipStream_t stream) {
  const float* X = (const float*)d_in[0];
  const float* Wv = (const float*)d_in[1];
  const float* Wth = (const float*)d_in[2];
  float* out = (float*)d_out;
  char* ws = (char*)d_ws;

  unsigned short* Xb = (unsigned short*)(ws);                  // 32 MB
  unsigned short* Xt = (unsigned short*)(ws + 33554432ull);    // 32 MB
  float* G_part = (float*)(ws + 67108864ull);                  // 41.94 MB
  unsigned short* Gb = (unsigned short*)(ws + 109051904ull);   // 2 MB
  unsigned short* Ht = (unsigned short*)(ws + 111149056ull);   // 2 MB
  unsigned short* kvt = (unsigned short*)(ws + 113246208ull);  // 2 MB
  unsigned short* Wvb = (unsigned short*)(ws + 115343360ull);  // 0.5 MB
  unsigned short* Wtb = (unsigned short*)(ws + 115867648ull);  // 0.5 MB
  float* mean_acc = (float*)(ws + 116391936ull);               // 8 KB
  float* meanV = (float*)(ws + 116400128ull);                  // 8 KB

  prep_w_kernel<<<257, 256, 0, stream>>>(Wv, Wth, Wvb, Wtb, mean_acc);
  prep_kernel<<<dim3(512, 8), 256, 0, stream>>>(X, Xb, Xt, mean_acc);

  g_gemm_kernel<<<dim3(10, 64), 256, 0, stream>>>(Xt, G_part);
  meanv_kernel<<<8, 256, 0, stream>>>(mean_acc, Wv, meanV);
  g_fin_kernel<<<320, 256, 0, stream>>>(G_part, Gb);

  gemm_rm_kernel<<<dim3(4, 4, 4), 256, 0, stream>>>(Wvb, Gb, Ht, 0, 262144);
  gemm_rm_kernel<<<dim3(4, 4, 4), 256, 0, stream>>>(Ht, Wtb, kvt, 262144, 0);

  gemm_out_kernel<<<dim3(256, 4), 256, 0, stream>>>(Xb, kvt, meanV, out);
}

// Round 4
// 254.046 us; speedup vs baseline: 1.3844x; 1.3844x over previous
//
#include <hip/hip_runtime.h>
#include <stdint.h>

// B=4, n=8192, d=512.  Algebraic form:
//   G_b = X_b^T X_b                       [512,512] sym, K=8192
//   kvt_b = Wv * (G_b*scale) * Wth^T      [e][d], scale = 1/(n*sqrt(d))
//   meanV_b[e] = colmean(X_b) . Wv[e][:]
//   out = X_b @ kvt_b(B-layout) + meanV
// Layouts (all K-inner for global_load_lds staging):
//   Xb  [32768][512] bf16        A for final GEMM
//   Xt  [4][512][8192] bf16      A=B for G GEMM (n-inner)
//   Gb  [4][512][512] bf16       scaled, full (mirrored from upper tiles)

typedef __bf16 bf16x8 __attribute__((ext_vector_type(8)));
typedef float f32x4 __attribute__((ext_vector_type(4)));
typedef unsigned short u16x4 __attribute__((ext_vector_type(4)));
typedef unsigned short u16x8 __attribute__((ext_vector_type(8)));

#define BM 128
#define BN 128
#define BK 32

__device__ __forceinline__ unsigned short f2bf(float f) {
  union { float f; unsigned int u; } c; c.f = f;
  unsigned int u = c.u;
  return (unsigned short)((u + 0x7FFFu + ((u >> 16) & 1u)) >> 16);  // RNE
}
__device__ __forceinline__ float bf2f(unsigned short h) {
  union { unsigned int u; float f; } c; c.u = ((unsigned int)h) << 16;
  return c.f;
}

__device__ __forceinline__ void gld16(const void* g, void* l) {
  using gptr_t = const __attribute__((address_space(1))) void*;
  using lptr_t = __attribute__((address_space(3))) void*;
  __builtin_amdgcn_global_load_lds((gptr_t)(uintptr_t)g,
                                   (lptr_t)(uint32_t)(uintptr_t)l, 16, 0, 0);
}

// 128x128 tile GEMM core: C[m][n] = sum_k A[m0+m][k] * B[n0+n][k]
// Two BK=32 tiles staged per barrier pair (halves barrier drains).
// K must be a multiple of 64. If sameAB, B staging is skipped (B==A tile).
__device__ __forceinline__ void gemm_tile(const unsigned short* __restrict__ A, int lda,
                                          const unsigned short* __restrict__ B, int ldb,
                                          int K, int m0, int n0, f32x4 (&acc)[4][4],
                                          bool sameAB) {
  __shared__ unsigned short sA[2][BM * BK];
  __shared__ unsigned short sB[2][BN * BK];
  const int tid = threadIdx.x;
  const int lane = tid & 63;
  const int w = tid >> 6;
  const int wm = w >> 1, wn = w & 1;
  const int quad = lane >> 4, l16 = lane & 15;

#pragma unroll
  for (int mi = 0; mi < 4; mi++)
#pragma unroll
    for (int ni = 0; ni < 4; ni++) acc[mi][ni] = f32x4{0.f, 0.f, 0.f, 0.f};

  for (int kt = 0; kt < K; kt += 2 * BK) {
#pragma unroll
    for (int h = 0; h < 2; h++) {
#pragma unroll
      for (int j = 0; j < 2; j++) {
        const int slot = w * 128 + j * 64 + lane;
        const int row = slot >> 2;
        const int col = (slot & 3) * 8;
        const int kc = kt + h * BK + col;
        gld16(A + (size_t)(m0 + row) * lda + kc,
              (char*)sA[h] + (size_t)(w * 128 + j * 64) * 16);
        if (!sameAB)
          gld16(B + (size_t)(n0 + row) * ldb + kc,
                (char*)sB[h] + (size_t)(w * 128 + j * 64) * 16);
      }
    }
    __syncthreads();

#pragma unroll
    for (int h = 0; h < 2; h++) {
      const unsigned short* bs = sameAB ? sA[h] : sB[h];
      bf16x8 af[4], bfr[4];
#pragma unroll
      for (int mi = 0; mi < 4; mi++)
        af[mi] = *(const bf16x8*)&sA[h][(wm * 64 + mi * 16 + l16) * BK + quad * 8];
#pragma unroll
      for (int ni = 0; ni < 4; ni++)
        bfr[ni] = *(const bf16x8*)&bs[(wn * 64 + ni * 16 + l16) * BK + quad * 8];
#pragma unroll
      for (int mi = 0; mi < 4; mi++)
#pragma unroll
        for (int ni = 0; ni < 4; ni++)
          acc[mi][ni] = __builtin_amdgcn_mfma_f32_16x16x32_bf16(af[mi], bfr[ni],
                                                                acc[mi][ni], 0, 0, 0);
    }
    __syncthreads();
  }
}

// ---- prep: X fp32 -> Xb bf16 + Xt bf16 (per-batch transpose), NO atomics ----
__global__ __launch_bounds__(256) void prep_kernel(const float* __restrict__ X,
                                                   unsigned short* __restrict__ Xb,
                                                   unsigned short* __restrict__ Xt) {
  __shared__ unsigned short sT[64 * 64];
  const int t = threadIdx.x;
  const int n0 = blockIdx.x * 64, d0 = blockIdx.y * 64;
  const int b = n0 >> 13, nb = n0 & 8191;
  const int r0 = (t >> 4) * 4, c0 = (t & 15) * 4;
  f32x4 v[4];
#pragma unroll
  for (int i = 0; i < 4; i++)
    v[i] = *(const f32x4*)(X + (size_t)(n0 + r0 + i) * 512 + d0 + c0);
  // Xb (row-major cast), coalesced 8B stores
#pragma unroll
  for (int i = 0; i < 4; i++) {
    u16x4 o;
#pragma unroll
    for (int j = 0; j < 4; j++) o[j] = f2bf(v[i][j]);
    *(u16x4*)(Xb + (size_t)(n0 + r0 + i) * 512 + d0 + c0) = o;
  }
  // transposed into LDS, XOR swizzle in 8-elem blocks (keeps u16x8 reads aligned)
#pragma unroll
  for (int j = 0; j < 4; j++) {
    u16x4 wv;
#pragma unroll
    for (int i = 0; i < 4; i++) wv[i] = f2bf(v[i][j]);
    const int c = c0 + j;
    const int rsw = r0 ^ (c & 0x38);
    *(u16x4*)&sT[c * 64 + rsw] = wv;
  }
  __syncthreads();
  // Xt stores: thread t -> rows c, c+32 (d-index), 8 n-elems each, 16B stores
  const int cr = t >> 3, p = t & 7;
#pragma unroll
  for (int h = 0; h < 2; h++) {
    const int c = cr + h * 32;
    const int phys = (p * 8) ^ (c & 0x38);
    u16x8 val = *(const u16x8*)&sT[c * 64 + phys];
    *(u16x8*)(Xt + (size_t)(b * 512 + d0 + c) * 8192 + nb + p * 8) = val;
  }
}

// ---- W casts, one launch ----
__global__ __launch_bounds__(256) void prep_w_kernel(const float* __restrict__ Wv,
                                                     const float* __restrict__ Wth,
                                                     unsigned short* __restrict__ Wvb,
                                                     unsigned short* __restrict__ Wtb) {
  const int blk = blockIdx.x;
  const int t = threadIdx.x;
  const float* src = (blk < 128) ? Wv : Wth;
  unsigned short* dst = (blk < 128) ? Wvb : Wtb;
  const int i = (blk & 127) * 256 + t;
  const f32x4* pp = (const f32x4*)(src + (size_t)i * 8);
  f32x4 v0 = pp[0], v1 = pp[1];
  u16x8 o;
  o[0] = f2bf(v0[0]); o[1] = f2bf(v0[1]); o[2] = f2bf(v0[2]); o[3] = f2bf(v0[3]);
  o[4] = f2bf(v1[0]); o[5] = f2bf(v1[1]); o[6] = f2bf(v1[2]); o[7] = f2bf(v1[3]);
  *(u16x8*)(dst + (size_t)i * 8) = o;
}

// ---- G = Xt Xt^T (per batch), split-K=16, upper tiles only ----
static __device__ const int TI[10] = {0, 0, 0, 0, 1, 1, 1, 2, 2, 3};
static __device__ const int TJ[10] = {0, 1, 2, 3, 1, 2, 3, 2, 3, 3};

__global__ __launch_bounds__(256) void g_gemm_kernel(const unsigned short* __restrict__ Xt,
                                                     float* __restrict__ G_part) {
  const int t = blockIdx.x;        // 0..9 upper tile
  const int z = blockIdx.y;        // b*16 + s
  const int b = z >> 4, s = z & 15;
  const int m0 = TI[t] * 128, n0 = TJ[t] * 128;
  const unsigned short* A = Xt + (size_t)b * 512 * 8192 + (size_t)s * 512;
  f32x4 acc[4][4];
  gemm_tile(A, 8192, A, 8192, 512, m0, n0, acc, m0 == n0);
  float* Cp = G_part + ((size_t)z * 10 + t) * 16384;  // tile stored [n_local][m_local]
  const int tid = threadIdx.x, lane = tid & 63, w = tid >> 6;
  const int wm = w >> 1, wn = w & 1, quad = lane >> 4, l16 = lane & 15;
#pragma unroll
  for (int mi = 0; mi < 4; mi++)
#pragma unroll
    for (int ni = 0; ni < 4; ni++) {
      const int ml = wm * 64 + mi * 16 + quad * 4;
      const int nl = wn * 64 + ni * 16 + l16;
      *(f32x4*)(Cp + (size_t)nl * 128 + ml) = acc[mi][ni];
    }
}

// sum slices, scale, cast bf16, write G + mirror
__global__ __launch_bounds__(256) void g_fin_kernel(const float* __restrict__ G_part,
                                                    unsigned short* __restrict__ Gb) {
  const int blk = blockIdx.x;  // 4*10*8
  const int b = blk / 80, rem = blk % 80;
  const int t = rem >> 3, cc = rem & 7;
  const int i = TI[t], j = TJ[t];
  const int m0 = i * 128, n0 = j * 128;
  const int tid = threadIdx.x;
  const int np = cc * 16 + (tid >> 4);
  const int mp = (tid & 15) * 8;
  f32x4 s0 = f32x4{0.f, 0.f, 0.f, 0.f}, s1 = f32x4{0.f, 0.f, 0.f, 0.f};
#pragma unroll
  for (int s = 0; s < 16; s++) {
    const float* p = G_part + (((size_t)(b * 16 + s)) * 10 + t) * 16384 + (size_t)np * 128 + mp;
    s0 += *(const f32x4*)p;
    s1 += *(const f32x4*)(p + 4);
  }
  const float scale = (float)(1.0 / (8192.0 * 22.627416997969522));
  unsigned short h[8];
#pragma unroll
  for (int r = 0; r < 4; r++) { h[r] = f2bf(s0[r] * scale); h[r + 4] = f2bf(s1[r] * scale); }
  unsigned short* Gbb = Gb + (size_t)b * 262144;
#pragma unroll
  for (int r = 0; r < 8; r++)
    Gbb[(size_t)(m0 + mp + r) * 512 + (n0 + np)] = h[r];
  if (i != j) {
    u16x8 o;
#pragma unroll
    for (int r = 0; r < 8; r++) o[r] = h[r];
    *(u16x8*)(Gbb + (size_t)(n0 + np) * 512 + (m0 + mp)) = o;
  }
}

// small batched GEMM, row-major bf16 C: C[m][n] = sum_k A[m][k]B[n][k], all 512
__global__ __launch_bounds__(256) void gemm_rm_kernel(const unsigned short* __restrict__ A,
                                                      const unsigned short* __restrict__ B,
                                                      unsigned short* __restrict__ C,
                                                      size_t Abs, size_t Bbs) {
  const int b = blockIdx.z;
  const int m0 = blockIdx.x * BM, n0 = blockIdx.y * BN;
  f32x4 acc[4][4];
  gemm_tile(A + (size_t)b * Abs, 512, B + (size_t)b * Bbs, 512, 512, m0, n0, acc, false);
  unsigned short* Cb = C + (size_t)b * 262144;
  const int tid = threadIdx.x, lane = tid & 63, w = tid >> 6;
  const int wm = w >> 1, wn = w & 1, quad = lane >> 4, l16 = lane & 15;
#pragma unroll
  for (int mi = 0; mi < 4; mi++)
#pragma unroll
    for (int ni = 0; ni < 4; ni++) {
      const int m = m0 + wm * 64 + mi * 16 + quad * 4;
      const int n = n0 + wn * 64 + ni * 16 + l16;
#pragma unroll
      for (int r = 0; r < 4; r++)
        Cb[(size_t)(m + r) * 512 + n] = f2bf(acc[mi][ni][r]);
    }
}

// final: out[m][e] = sum_d Xb[m][d]*kvt_b[e][d] + meanV[b][e]
__global__ __launch_bounds__(256) void gemm_out_kernel(
    const unsigned short* __restrict__ Xb, const unsigned short* __restrict__ kvt,
    const float* __restrict__ meanV, float* __restrict__ out) {
  const int m0 = blockIdx.x * BM, n0 = blockIdx.y * BN;
  const int b = blockIdx.x >> 6;
  const unsigned short* Bm = kvt + (size_t)b * 262144;
  f32x4 acc[4][4];
  gemm_tile(Xb, 512, Bm, 512, 512, m0, n0, acc, false);
  const int tid = threadIdx.x, lane = tid & 63, w = tid >> 6;
  const int wm = w >> 1, wn = w & 1, quad = lane >> 4, l16 = lane & 15;
#pragma unroll
  for (int ni = 0; ni < 4; ni++) {
    const int e = n0 + wn * 64 + ni * 16 + l16;
    const float mu = meanV[b * 512 + e];
#pragma unroll
    for (int mi = 0; mi < 4; mi++) {
      const int m = m0 + wm * 64 + mi * 16 + quad * 4;
#pragma unroll
      for (int r = 0; r < 4; r++)
        out[(size_t)(m + r) * 512 + e] = acc[mi][ni][r] + mu;
    }
  }
}

// mean_x[b*512+d] = (1/8192) sum_n Xt[b][d][n]
__global__ __launch_bounds__(256) void meanx_kernel(const unsigned short* __restrict__ Xt,
                                                    float* __restrict__ mean_x) {
  const int be = blockIdx.x;
  const unsigned short* row = Xt + (size_t)be * 8192;
  const int t = threadIdx.x;
  float s = 0.f;
  for (int c = t; c < 1024; c += 256) {
    u16x8 v = *(const u16x8*)(row + c * 8);
#pragma unroll
    for (int j = 0; j < 8; j++) s += bf2f(v[j]);
  }
  __shared__ float red[256];
  red[t] = s;
  __syncthreads();
  for (int st = 128; st > 0; st >>= 1) {
    if (t < st) red[t] += red[t + st];
    __syncthreads();
  }
  if (t == 0) mean_x[be] = red[0] * (1.f / 8192.f);
}

// meanV[b*512+e] = sum_d mean_x[b*512+d] * Wv[e*512+d]  (fp32 inputs)
__global__ __launch_bounds__(256) void meanv_kernel(const float* __restrict__ mean_x,
                                                    const float* __restrict__ Wv,
                                                    float* __restrict__ meanV) {
  const int idx = blockIdx.x * 256 + threadIdx.x;
  const int b = idx >> 9, e = idx & 511;
  const float* mx = mean_x + b * 512;
  const float* wr = Wv + (size_t)e * 512;
  float s = 0.f;
  for (int d = 0; d < 512; d += 4) {
    f32x4 a = *(const f32x4*)(mx + d);
    f32x4 w = *(const f32x4*)(wr + d);
    s += a[0] * w[0] + a[1] * w[1] + a[2] * w[2] + a[3] * w[3];
  }
  meanV[idx] = s;
}

extern "C" void kernel_launch(void* const* d_in, const int* in_sizes, int n_in,
                              void* d_out, int out_size, void* d_ws, size_t ws_size,
                              hipStream_t stream) {
  const float* X = (const float*)d_in[0];
  const float* Wv = (const float*)d_in[1];
  const float* Wth = (const float*)d_in[2];
  float* out = (float*)d_out;
  char* ws = (char*)d_ws;

  unsigned short* Xb = (unsigned short*)(ws);                  // 32 MB
  unsigned short* Xt = (unsigned short*)(ws + 33554432ull);    // 32 MB
  float* G_part = (float*)(ws + 67108864ull);                  // 41.94 MB
  unsigned short* Gb = (unsigned short*)(ws + 109051904ull);   // 2 MB
  unsigned short* Ht = (unsigned short*)(ws + 111149056ull);   // 2 MB
  unsigned short* kvt = (unsigned short*)(ws + 113246208ull);  // 2 MB
  unsigned short* Wvb = (unsigned short*)(ws + 115343360ull);  // 0.5 MB
  unsigned short* Wtb = (unsigned short*)(ws + 115867648ull);  // 0.5 MB
  float* mean_x = (float*)(ws + 116391936ull);                 // 8 KB
  float* meanV = (float*)(ws + 116400128ull);                  // 8 KB

  prep_w_kernel<<<256, 256, 0, stream>>>(Wv, Wth, Wvb, Wtb);
  prep_kernel<<<dim3(512, 8), 256, 0, stream>>>(X, Xb, Xt);

  g_gemm_kernel<<<dim3(10, 64), 256, 0, stream>>>(Xt, G_part);
  meanx_kernel<<<2048, 256, 0, stream>>>(Xt, mean_x);
  meanv_kernel<<<8, 256, 0, stream>>>(mean_x, Wv, meanV);
  g_fin_kernel<<<320, 256, 0, stream>>>(G_part, Gb);

  gemm_rm_kernel<<<dim3(4, 4, 4), 256, 0, stream>>>(Wvb, Gb, Ht, 0, 262144);
  gemm_rm_kernel<<<dim3(4, 4, 4), 256, 0, stream>>>(Ht, Wtb, kvt, 262144, 0);

  gemm_out_kernel<<<dim3(256, 4), 256, 0, stream>>>(Xb, kvt, meanV, out);
}